// Round 1
// baseline (295.217 us; speedup 1.0000x reference)
//
#include <hip/hip_runtime.h>
#include <cstdint>
#include <cstddef>

// Problem constants
#define B_SZ   64
#define IN_CH  32
#define OUT_CH 32
#define NMAPS  64
#define HW     4096          // 64*64
#define CTRLN  512
#define NF_    64
#define NI_    2048
#define NO_    2048
#define NROWS  4160          // NF+NI+NO
#define OUT0_SZ (B_SZ*OUT_CH*HW)   // 8388608 floats (outputs), then new_state

// ws layout (floats):
//   f[b][m]           : 64*64            @ F_OFF
//   ig_t[b][c][m]     : 64*32*64         @ IG_OFF   (c-major so m is contiguous)
//   og_t[b][m][o]     : 64*64*32         @ OG_OFF   (m-major so o is contiguous)
#define F_OFF  0
#define IG_OFF (64*64)
#define OG_OFF (64*64 + 64*32*64)
// total = 266240 floats = 1.04 MB

// Kernel 1: ctrl = controls @ W^T, scattered into transposed gate layouts.
__global__ __launch_bounds__(256) void ctrl_gemm(
    const float* __restrict__ controls, const float* __restrict__ W,
    float* __restrict__ ws)
{
    __shared__ __align__(16) float ctl[CTRLN];
    const int b   = blockIdx.y;
    const int tid = threadIdx.x;
    for (int k = tid; k < CTRLN; k += 256) ctl[k] = controls[b * CTRLN + k];
    __syncthreads();

    const int j = blockIdx.x * 256 + tid;
    if (j >= NROWS) return;

    const float4* wr = (const float4*)(W + (size_t)j * CTRLN);
    const float4* cl = (const float4*)ctl;
    float acc = 0.f;
#pragma unroll 4
    for (int k = 0; k < CTRLN / 4; ++k) {
        float4 w4 = wr[k];
        float4 c4 = cl[k];
        acc += w4.x * c4.x + w4.y * c4.y + w4.z * c4.z + w4.w * c4.w;
    }

    if (j < NF_) {
        ws[F_OFF + b * 64 + j] = acc;
    } else if (j < NF_ + NI_) {
        const int jj = j - NF_;
        const int m = jj >> 5;        // /32
        const int c = jj & 31;
        ws[IG_OFF + (b * 32 + c) * 64 + m] = acc;
    } else {
        const int jj = j - NF_ - NI_;
        const int o = jj >> 6;        // /64
        const int m = jj & 63;
        ws[OG_OFF + (b * 64 + m) * 32 + o] = acc;
    }
}

// Kernel 2: fused gated-input matmul + forget gate + tanh + output matmul.
// Block = (batch b, tile of 64 spatial positions). 256 threads = 4 waves.
// Wave w (ty = tid>>6) owns maps [ty*16, ty*16+16) in phase A and output
// channels [ty*8, ty*8+8) in phase B; lane tx = position within tile.
__global__ __launch_bounds__(256) void vstm_main(
    const float* __restrict__ inputs, const float* __restrict__ state,
    const float* __restrict__ ws, float* __restrict__ out)
{
    __shared__ __align__(16) float Xs[IN_CH][64];   // 8 KB input tile
    __shared__ __align__(16) float Ts[NMAPS][64];   // 16 KB tanh(new_state) tile

    const int tid  = threadIdx.x;
    const int b    = blockIdx.y;
    const int tile = blockIdx.x * 64;
    const int tx   = tid & 63;
    // wave-uniform (waves are 64 consecutive tids) -> forces SGPR, so gate
    // loads below become scalar s_load with SGPR-operand v_fmac.
    const int ty   = __builtin_amdgcn_readfirstlane(tid >> 6);

    // Stage the 32 x 64 input tile (coalesced: 64-consecutive-float rows).
    const float* inb = inputs + (size_t)b * IN_CH * HW + tile;
    for (int idx = tid; idx < IN_CH * 64; idx += 256) {
        const int c = idx >> 6, p = idx & 63;
        Xs[c][p] = inb[c * HW + p];
    }
    __syncthreads();

    // ---------------- Phase A: gated = in_gates @ X, + state*f, tanh -------
    const float* fg = ws + F_OFF + b * 64 + ty * 16;           // 16 forget gates
    const float* ig = ws + IG_OFF + (size_t)(b * 32) * 64 + ty * 16; // ig[c*64 + j]

    float acc[16];
#pragma unroll
    for (int j = 0; j < 16; ++j) acc[j] = 0.f;

#pragma unroll 8
    for (int c = 0; c < IN_CH; ++c) {
        const float x = Xs[c][tx];
#pragma unroll
        for (int j = 0; j < 16; ++j) acc[j] += ig[c * 64 + j] * x;
    }

    const float* stb    = state + (size_t)b * NMAPS * HW + tile;
    float*       ns_out = out + OUT0_SZ + (size_t)b * NMAPS * HW + tile;
#pragma unroll
    for (int j = 0; j < 16; ++j) {
        const int m = ty * 16 + j;
        const float ns = acc[j] + stb[m * HW + tx] * fg[j];
        ns_out[m * HW + tx] = ns;
        Ts[m][tx] = tanhf(ns);
    }
    __syncthreads();

    // ---------------- Phase B: outputs = out_gates @ tanh tile -------------
    const float* og = ws + OG_OFF + (size_t)(b * 64) * 32 + ty * 8; // og[m*32 + j]
    float acc2[8];
#pragma unroll
    for (int j = 0; j < 8; ++j) acc2[j] = 0.f;

#pragma unroll 8
    for (int m = 0; m < NMAPS; ++m) {
        const float t = Ts[m][tx];
#pragma unroll
        for (int j = 0; j < 8; ++j) acc2[j] += og[m * 32 + j] * t;
    }

    float* ob = out + (size_t)b * OUT_CH * HW + tile;
#pragma unroll
    for (int j = 0; j < 8; ++j) {
        ob[(ty * 8 + j) * HW + tx] = acc2[j];
    }
}

extern "C" void kernel_launch(void* const* d_in, const int* in_sizes, int n_in,
                              void* d_out, int out_size, void* d_ws, size_t ws_size,
                              hipStream_t stream) {
    const float* inputs   = (const float*)d_in[0];
    const float* state    = (const float*)d_in[1];
    const float* controls = (const float*)d_in[2];
    const float* W        = (const float*)d_in[3];
    float*       out      = (float*)d_out;
    float*       ws       = (float*)d_ws;

    dim3 g1((NROWS + 255) / 256, B_SZ);
    ctrl_gemm<<<g1, 256, 0, stream>>>(controls, W, ws);

    dim3 g2(HW / 64, B_SZ);
    vstm_main<<<g2, 256, 0, stream>>>(inputs, state, ws, out);
}

// Round 2
// 228.209 us; speedup vs baseline: 1.2936x; 1.2936x over previous
//
#include <hip/hip_runtime.h>
#include <cstdint>
#include <cstddef>

// Problem constants
#define B_SZ   64
#define IN_CH  32
#define OUT_CH 32
#define NMAPS  64
#define HW     4096          // 64*64
#define CTRLN  512
#define NROWS  4160          // NF(64) + NI(2048) + NO(2048)
#define OUT0_SZ (B_SZ*OUT_CH*HW)   // outputs come first in d_out, then new_state
#define TILE   128

// ws layout: ctrl[b][j], j in original gate order (f:0..63, i:64..2111, o:2112..4159)
// total 64*4160 floats = 1.065 MB

__device__ __forceinline__ float fast_tanh(float x) {
    // tanh(x) = 1 - 2/(exp(2x)+1); exact at +/-inf, ~1e-6 rel err.
    float e = __expf(2.0f * x);
    return 1.0f - 2.0f * __builtin_amdgcn_rcpf(e + 1.0f);
}

// ---------------------------------------------------------------------------
// Kernel 1: ctrl = controls @ W^T.  Batch in lanes (B=64 == wave size), so
// W-row addresses are wave-uniform -> scalar s_load broadcast; controls reads
// are lane-strided but L1-served (each 128B line reused across 8 float4 iters).
// Each wave computes 4 rows x 64 batches.  Grid: 4160/16 = 260 blocks.
// ---------------------------------------------------------------------------
__global__ __launch_bounds__(256) void ctrl_gemm(
    const float* __restrict__ controls, const float* __restrict__ W,
    float* __restrict__ ws)
{
    const int tid = threadIdx.x;
    const int b   = tid & 63;
    const int w   = __builtin_amdgcn_readfirstlane(tid >> 6);
    const int j0  = blockIdx.x * 16 + w * 4;

    const float4* cb = (const float4*)(controls + b * CTRLN);
    const float*  w0 = W + (size_t)j0 * CTRLN;

    float acc[4] = {0.f, 0.f, 0.f, 0.f};
#pragma unroll 4
    for (int kk = 0; kk < CTRLN / 4; ++kk) {
        float4 x = cb[kk];
#pragma unroll
        for (int r = 0; r < 4; ++r) {
            float4 wv = *(const float4*)(w0 + r * CTRLN + kk * 4);
            acc[r] += wv.x * x.x + wv.y * x.y + wv.z * x.z + wv.w * x.w;
        }
    }
    float* wb = ws + (size_t)b * NROWS + j0;
#pragma unroll
    for (int r = 0; r < 4; ++r) wb[r] = acc[r];
}

// ---------------------------------------------------------------------------
// Kernel 2: fused gated-input matmul + forget gate + tanh + output matmul.
// Block = (batch b, 128 spatial positions). 256 threads = 4 waves.
// Gates staged in LDS once per block (transposed, padded); thread owns
// 2 positions so each broadcast gate read feeds 2 FMAs.
// LDS: union(Xs 16KB, Ts 32KB) + igs 8.5KB + ogs 9KB + fs -> 50.9KB,
// 3 blocks/CU.
// ---------------------------------------------------------------------------
__global__ __launch_bounds__(256, 3) void vstm_main(
    const float* __restrict__ inputs, const float* __restrict__ state,
    const float* __restrict__ ws, float* __restrict__ out)
{
    __shared__ __align__(16) float uni[64 * TILE];      // Xs[32][128] then Ts[64][128]
    __shared__ __align__(16) float igs[32 * 68];        // igs[c][m], pad 68 (16B-aligned, few conflicts)
    __shared__ __align__(16) float ogs[64 * 36];        // ogs[m][o], pad 36
    __shared__ __align__(16) float fs[64];

    const int tid  = threadIdx.x;
    const int b    = blockIdx.y;
    const int tile = blockIdx.x * TILE;
    const int tx   = tid & 63;
    const int wy   = __builtin_amdgcn_readfirstlane(tid >> 6);  // wave id 0..3

    // ---- stage gates (coalesced reads from ws, transposed LDS writes) ----
    const float* g = ws + (size_t)b * NROWS;
    if (tid < 64) fs[tid] = g[tid];
#pragma unroll
    for (int i = 0; i < 8; ++i) {
        const int idx = i * 256 + tid;                  // 0..2047
        // in_gates: ctrl[64 + m*32 + c] -> igs[c][m]
        igs[(idx & 31) * 68 + (idx >> 5)] = g[64 + idx];
        // out_gates: ctrl[2112 + o*64 + m] -> ogs[m][o]
        ogs[(idx & 63) * 36 + (idx >> 6)] = g[2112 + idx];
    }

    // ---- stage input tile Xs[32][128] (float4 coalesced) ----
    const float* inb = inputs + (size_t)b * IN_CH * HW + tile;
    float4* Xs4 = (float4*)uni;
#pragma unroll
    for (int i = 0; i < 4; ++i) {
        const int idx = i * 256 + tid;                  // float4 index 0..1023
        const int c = idx >> 5, p4 = idx & 31;          // 32 float4 per row
        Xs4[c * 32 + p4] = *(const float4*)(inb + c * HW + p4 * 4);
    }
    __syncthreads();

    // ---- Phase A: gated[m][p] = sum_c ig[m][c] * X[c][p] ----
    const int m0 = wy * 16;
    float acc0[16], acc1[16];
#pragma unroll
    for (int j = 0; j < 16; ++j) { acc0[j] = 0.f; acc1[j] = 0.f; }

#pragma unroll 8
    for (int c = 0; c < IN_CH; ++c) {
        const float x0 = uni[c * TILE + tx];
        const float x1 = uni[c * TILE + 64 + tx];
        float gg[16];
        const float4* gp = (const float4*)&igs[c * 68 + m0];  // wave-uniform broadcast
        *(float4*)&gg[0]  = gp[0];
        *(float4*)&gg[4]  = gp[1];
        *(float4*)&gg[8]  = gp[2];
        *(float4*)&gg[12] = gp[3];
#pragma unroll
        for (int j = 0; j < 16; ++j) {
            acc0[j] += gg[j] * x0;
            acc1[j] += gg[j] * x1;
        }
    }

    // ---- forget gate + new_state store + tanh ----
    float fr[16];
    *(float4*)&fr[0]  = *(const float4*)&fs[m0];
    *(float4*)&fr[4]  = *(const float4*)&fs[m0 + 4];
    *(float4*)&fr[8]  = *(const float4*)&fs[m0 + 8];
    *(float4*)&fr[12] = *(const float4*)&fs[m0 + 12];

    const float* stb = state + (size_t)b * NMAPS * HW + tile;
    float*       nsb = out + OUT0_SZ + (size_t)b * NMAPS * HW + tile;
    float t0[16], t1[16];
#pragma unroll
    for (int j = 0; j < 16; ++j) {
        const int m = m0 + j;
        const float ns0 = acc0[j] + stb[m * HW + tx]      * fr[j];
        const float ns1 = acc1[j] + stb[m * HW + 64 + tx] * fr[j];
        nsb[m * HW + tx]      = ns0;
        nsb[m * HW + 64 + tx] = ns1;
        t0[j] = fast_tanh(ns0);
        t1[j] = fast_tanh(ns1);
    }
    __syncthreads();   // all Xs reads done -> safe to overwrite uni with Ts

#pragma unroll
    for (int j = 0; j < 16; ++j) {
        uni[(m0 + j) * TILE + tx]      = t0[j];
        uni[(m0 + j) * TILE + 64 + tx] = t1[j];
    }
    __syncthreads();

    // ---- Phase B: out[o][p] = sum_m og[o][m] * T[m][p] ----
    const int o0 = wy * 8;
    float bacc0[8], bacc1[8];
#pragma unroll
    for (int j = 0; j < 8; ++j) { bacc0[j] = 0.f; bacc1[j] = 0.f; }

#pragma unroll 8
    for (int m = 0; m < NMAPS; ++m) {
        const float u0 = uni[m * TILE + tx];
        const float u1 = uni[m * TILE + 64 + tx];
        float og[8];
        *(float4*)&og[0] = *(const float4*)&ogs[m * 36 + o0];      // wave-uniform
        *(float4*)&og[4] = *(const float4*)&ogs[m * 36 + o0 + 4];
#pragma unroll
        for (int j = 0; j < 8; ++j) {
            bacc0[j] += og[j] * u0;
            bacc1[j] += og[j] * u1;
        }
    }

    float* ob = out + (size_t)b * OUT_CH * HW + tile;
#pragma unroll
    for (int j = 0; j < 8; ++j) {
        ob[(o0 + j) * HW + tx]      = bacc0[j];
        ob[(o0 + j) * HW + 64 + tx] = bacc1[j];
    }
}

extern "C" void kernel_launch(void* const* d_in, const int* in_sizes, int n_in,
                              void* d_out, int out_size, void* d_ws, size_t ws_size,
                              hipStream_t stream) {
    const float* inputs   = (const float*)d_in[0];
    const float* state    = (const float*)d_in[1];
    const float* controls = (const float*)d_in[2];
    const float* W        = (const float*)d_in[3];
    float*       out      = (float*)d_out;
    float*       ws       = (float*)d_ws;

    ctrl_gemm<<<dim3(NROWS / 16), 256, 0, stream>>>(controls, W, ws);

    dim3 g2(HW / TILE, B_SZ);
    vstm_main<<<g2, 256, 0, stream>>>(inputs, state, ws, out);
}

// Round 3
// 227.753 us; speedup vs baseline: 1.2962x; 1.0020x over previous
//
#include <hip/hip_runtime.h>
#include <cstdint>
#include <cstddef>

// Problem constants
#define B_SZ   64
#define IN_CH  32
#define OUT_CH 32
#define NMAPS  64
#define HW     4096          // 64*64
#define CTRLN  512
#define NROWS  4160          // NF(64) + NI(2048) + NO(2048)
#define OUT0_SZ (B_SZ*OUT_CH*HW)
#define TILE   128

typedef short bf8_t  __attribute__((ext_vector_type(8)));   // 8 bf16 = 4 VGPR
typedef float f32x4  __attribute__((ext_vector_type(4)));

__device__ __forceinline__ unsigned short f2bf(float f) {
    union { float f; uint32_t u; } v; v.f = f;
    return (unsigned short)((v.u + 0x7FFFu + ((v.u >> 16) & 1u)) >> 16);  // RNE
}
__device__ __forceinline__ float fast_tanh(float x) {
    float e = __expf(2.0f * x);               // tanh = 1 - 2/(e^{2x}+1)
    return 1.0f - 2.0f * __builtin_amdgcn_rcpf(e + 1.0f);
}

// ---------------------------------------------------------------------------
// Kernel 1: ctrl = controls @ W^T.  controls staged TRANSPOSED in LDS
// (ct[k][b], pad 65 -> conflict-free lane-per-batch reads); W rows are
// wave-uniform -> s_load broadcast.  Block = 16 rows, wave = 4 rows.
// ---------------------------------------------------------------------------
__global__ __launch_bounds__(256) void ctrl_gemm(
    const float* __restrict__ controls, const float* __restrict__ W,
    float* __restrict__ ws)
{
    __shared__ __align__(16) float ct[128 * 65];
    const int tid = threadIdx.x;
    const int b   = tid & 63;
    const int w   = __builtin_amdgcn_readfirstlane(tid >> 6);
    const int j0  = blockIdx.x * 16 + w * 4;
    const float* w0 = W + (size_t)j0 * CTRLN;

    float acc[4] = {0.f, 0.f, 0.f, 0.f};
    for (int kc = 0; kc < CTRLN; kc += 128) {
        __syncthreads();
#pragma unroll
        for (int i = 0; i < 8; ++i) {
            const int flat = (i * 256 + tid) * 4;   // 0..32767
            const int bb = flat >> 7;               // batch
            const int kk = flat & 127;              // k within chunk
            float4 v = *(const float4*)(controls + (size_t)bb * CTRLN + kc + kk);
            ct[(kk + 0) * 65 + bb] = v.x;
            ct[(kk + 1) * 65 + bb] = v.y;
            ct[(kk + 2) * 65 + bb] = v.z;
            ct[(kk + 3) * 65 + bb] = v.w;
        }
        __syncthreads();
#pragma unroll 4
        for (int k = 0; k < 128; ++k) {
            const float c = ct[k * 65 + b];          // conflict-free b32
#pragma unroll
            for (int r = 0; r < 4; ++r)
                acc[r] += w0[r * CTRLN + kc + k] * c; // s_load operand
        }
    }
    float* wb = ws + (size_t)b * NROWS + j0;
#pragma unroll
    for (int r = 0; r < 4; ++r) wb[r] = acc[r];
}

// ---------------------------------------------------------------------------
// Kernel 2: MFMA-based fused kernel.  Block = (batch, 128 positions), 4 waves.
// Phase A: gated[m][p] = IG[m][c] x X[c][p]   (16x16x32 bf16, K=32 one step)
//   wave w owns m-rows [16w,16w+16) x all 8 p-chunks: 1 A-frag + 8 B-frag + 8 MFMA
// Epilogue: ns = acc + state*f (fp32), store ns, tanh -> Tt[p][m] bf16
// Phase B: out[o][p] = OG[o][m] x T[m][p]     (K=64 = 2 steps)
//   wave w owns (o-chunk w>>1, p-chunks 4*(w&1)..+4): 4 tiles x 2 MFMA
// LDS ~38.6 KB -> 4 blocks/CU.
// ---------------------------------------------------------------------------
__global__ __launch_bounds__(256, 4) void vstm_main(
    const float* __restrict__ inputs, const float* __restrict__ state,
    const float* __restrict__ ws, float* __restrict__ out)
{
    __shared__ __align__(16) unsigned short Xt[TILE * 40];  // X^T[p][c], pad 40
    __shared__ __align__(16) unsigned short IGs[64 * 40];   // IG[m][c],  pad 40
    __shared__ __align__(16) unsigned short OGs[32 * 72];   // OG[o][m],  pad 72
    __shared__ __align__(16) unsigned short Tt[TILE * 72];  // T^T[p][m], pad 72
    __shared__ __align__(16) float fs[64];

    const int tid  = threadIdx.x;
    const int b    = blockIdx.y;
    const int tile = blockIdx.x * TILE;
    const int w    = __builtin_amdgcn_readfirstlane(tid >> 6);
    const int l    = tid & 63;
    const int lhi  = l >> 4;     // quad 0..3
    const int llo  = l & 15;

    // ---- stage gates (coalesced global reads, bf16 LDS writes) ----
    const float* g = ws + (size_t)b * NROWS;
    if (tid < 64) fs[tid] = g[tid];
#pragma unroll
    for (int i = 0; i < 8; ++i) {
        const int idx = i * 256 + tid;                       // 0..2047
        IGs[(idx >> 5) * 40 + (idx & 31)] = f2bf(g[64 + idx]);
        OGs[(idx >> 6) * 72 + (idx & 63)] = f2bf(g[2112 + idx]);
    }
    // ---- stage X^T[p][c] (coalesced b32 reads, ~2-way LDS writes) ----
    const float* inb = inputs + (size_t)b * IN_CH * HW + tile;
#pragma unroll
    for (int i = 0; i < 16; ++i) {
        const int flat = i * 256 + tid;                      // 0..4095
        const int c = flat >> 7, p = flat & 127;
        Xt[p * 40 + c] = f2bf(inb[c * HW + p]);
    }
    __syncthreads();

    // ---- Phase A ----
    const bf8_t af = *(const bf8_t*)&IGs[(w * 16 + llo) * 40 + lhi * 8];
    f32x4 acc[8];
#pragma unroll
    for (int pc = 0; pc < 8; ++pc) {
        acc[pc] = (f32x4){0.f, 0.f, 0.f, 0.f};
        const bf8_t bf = *(const bf8_t*)&Xt[(pc * 16 + llo) * 40 + lhi * 8];
        acc[pc] = __builtin_amdgcn_mfma_f32_16x16x32_bf16(af, bf, acc[pc], 0, 0, 0);
    }

    // ---- epilogue: forget gate + new_state (fp32) + tanh -> Tt ----
    float fr[4];
#pragma unroll
    for (int r = 0; r < 4; ++r) fr[r] = fs[w * 16 + lhi * 4 + r];

    const float* stb = state + (size_t)b * NMAPS * HW + tile;
    float*       nsb = out + OUT0_SZ + (size_t)b * NMAPS * HW + tile;
#pragma unroll
    for (int pc = 0; pc < 8; ++pc) {
        const int p = pc * 16 + llo;
#pragma unroll
        for (int r = 0; r < 4; ++r) {
            const int m = w * 16 + lhi * 4 + r;              // C/D: row=quad*4+reg
            const float ns = acc[pc][r] + stb[m * HW + p] * fr[r];
            nsb[m * HW + p] = ns;
            Tt[p * 72 + m] = f2bf(fast_tanh(ns));
        }
    }
    __syncthreads();

    // ---- Phase B ----
    const int oc  = w >> 1;            // o-chunk 0..1
    const int pcb = (w & 1) * 4;       // p-chunk base
    bf8_t ag[2];
#pragma unroll
    for (int ks = 0; ks < 2; ++ks)
        ag[ks] = *(const bf8_t*)&OGs[(oc * 16 + llo) * 72 + ks * 32 + lhi * 8];

    f32x4 acc2[4];
#pragma unroll
    for (int t = 0; t < 4; ++t) {
        acc2[t] = (f32x4){0.f, 0.f, 0.f, 0.f};
        const int pc = pcb + t;
#pragma unroll
        for (int ks = 0; ks < 2; ++ks) {
            const bf8_t bt = *(const bf8_t*)&Tt[(pc * 16 + llo) * 72 + ks * 32 + lhi * 8];
            acc2[t] = __builtin_amdgcn_mfma_f32_16x16x32_bf16(ag[ks], bt, acc2[t], 0, 0, 0);
        }
    }

    float* ob = out + (size_t)b * OUT_CH * HW + tile;
#pragma unroll
    for (int t = 0; t < 4; ++t) {
        const int p = (pcb + t) * 16 + llo;
#pragma unroll
        for (int r = 0; r < 4; ++r) {
            const int o = oc * 16 + lhi * 4 + r;
            ob[o * HW + p] = acc2[t][r];
        }
    }
}

extern "C" void kernel_launch(void* const* d_in, const int* in_sizes, int n_in,
                              void* d_out, int out_size, void* d_ws, size_t ws_size,
                              hipStream_t stream) {
    const float* inputs   = (const float*)d_in[0];
    const float* state    = (const float*)d_in[1];
    const float* controls = (const float*)d_in[2];
    const float* W        = (const float*)d_in[3];
    float*       out      = (float*)d_out;
    float*       ws       = (float*)d_ws;

    ctrl_gemm<<<dim3(NROWS / 16), 256, 0, stream>>>(controls, W, ws);

    dim3 g2(HW / TILE, B_SZ);
    vstm_main<<<g2, 256, 0, stream>>>(inputs, state, ws, out);
}

// Round 4
// 224.676 us; speedup vs baseline: 1.3140x; 1.0137x over previous
//
#include <hip/hip_runtime.h>
#include <cstdint>
#include <cstddef>

// Problem constants
#define B_SZ   64
#define IN_CH  32
#define OUT_CH 32
#define NMAPS  64
#define HW     4096          // 64*64
#define CTRLN  512
#define NROWS  4160          // NF(64) + NI(2048) + NO(2048)
#define OUT0_SZ (B_SZ*OUT_CH*HW)
#define TILE   128

typedef short bf8_t  __attribute__((ext_vector_type(8)));   // 8 bf16 = 4 VGPR
typedef short bf4_t  __attribute__((ext_vector_type(4)));   // 4 bf16 = 2 VGPR
typedef float f32x4  __attribute__((ext_vector_type(4)));

__device__ __forceinline__ unsigned short f2bf(float f) {
    union { float f; uint32_t u; } v; v.f = f;
    return (unsigned short)((v.u + 0x7FFFu + ((v.u >> 16) & 1u)) >> 16);  // RNE
}
__device__ __forceinline__ float fast_tanh(float x) {
    float e = __expf(2.0f * x);               // tanh = 1 - 2/(e^{2x}+1)
    return 1.0f - 2.0f * __builtin_amdgcn_rcpf(e + 1.0f);
}

// ---------------------------------------------------------------------------
// Kernel 1: ctrl = controls @ W^T.  controls staged transposed in LDS
// (ct[k][b], pad 65 -> conflict-free lane-per-batch reads); W rows wave-
// uniform -> s_load broadcast.  2 rows/wave, 8 rows/block, 520 blocks for
// 2x the wave-level parallelism of R3 (latency-bound kernel).
// ---------------------------------------------------------------------------
__global__ __launch_bounds__(256) void ctrl_gemm(
    const float* __restrict__ controls, const float* __restrict__ W,
    float* __restrict__ ws)
{
    __shared__ __align__(16) float ct[128 * 65];
    const int tid = threadIdx.x;
    const int b   = tid & 63;
    const int w   = __builtin_amdgcn_readfirstlane(tid >> 6);
    const int j0  = blockIdx.x * 8 + w * 2;
    const float* w0 = W + (size_t)j0 * CTRLN;

    float acc0 = 0.f, acc1 = 0.f;
    for (int kc = 0; kc < CTRLN; kc += 128) {
        __syncthreads();
#pragma unroll
        for (int i = 0; i < 8; ++i) {
            const int flat = (i * 256 + tid) * 4;   // 0..32767
            const int bb = flat >> 7;               // batch
            const int kk = flat & 127;              // k within chunk
            float4 v = *(const float4*)(controls + (size_t)bb * CTRLN + kc + kk);
            ct[(kk + 0) * 65 + bb] = v.x;
            ct[(kk + 1) * 65 + bb] = v.y;
            ct[(kk + 2) * 65 + bb] = v.z;
            ct[(kk + 3) * 65 + bb] = v.w;
        }
        __syncthreads();
#pragma unroll 8
        for (int k = 0; k < 128; ++k) {
            const float c = ct[k * 65 + b];          // conflict-free b32
            acc0 += w0[kc + k] * c;                  // s_load operands
            acc1 += w0[CTRLN + kc + k] * c;
        }
    }
    ws[(size_t)b * NROWS + j0]     = acc0;
    ws[(size_t)b * NROWS + j0 + 1] = acc1;
}

// ---------------------------------------------------------------------------
// Kernel 2: MFMA fused kernel, OUTPUT-TRANSPOSED tiling: D[p][m] so each
// lane owns 4 consecutive positions (row = quad*4+reg) at fixed map ->
// all state/new_state/output global traffic is dwordx4, 16 full cache
// lines per instruction.
// Block = (batch, 128 positions), 4 waves; wave w owns p in [32w, 32w+32).
// Phase A: D[p][m] = X^T[p][c] x IG^T[c][m]      (A=Xt frag, B=IGs frag)
// Epilogue: ns = acc + state*f (fp32, float4 I/O), tanh -> Tt[p][m] bf16
// Phase B: D[p][o] = T^T[p][m] x OG^T[m][o]      (A=Tt frag, B=OGs frag)
// Wave-private p rows => NO barrier between epilogue and phase B.
// LDS ~38.9 KB -> 4 blocks/CU.
// ---------------------------------------------------------------------------
__global__ __launch_bounds__(256, 4) void vstm_main(
    const float* __restrict__ inputs, const float* __restrict__ state,
    const float* __restrict__ ws, float* __restrict__ out)
{
    __shared__ __align__(16) unsigned short Xt[TILE * 40];  // X^T[p][c], pad 40
    __shared__ __align__(16) unsigned short IGs[64 * 40];   // IG[m][c],  pad 40
    __shared__ __align__(16) unsigned short OGs[32 * 72];   // OG[o][m],  pad 72
    __shared__ __align__(16) unsigned short Tt[TILE * 72];  // T^T[p][m], pad 72
    __shared__ __align__(16) float fs[64];

    const int tid  = threadIdx.x;
    const int b    = blockIdx.y;
    const int tile = blockIdx.x * TILE;
    const int w    = __builtin_amdgcn_readfirstlane(tid >> 6);
    const int l    = tid & 63;
    const int quad = l >> 4;
    const int mlo  = l & 15;

    // ---- stage gates (float4 global reads, b64 LDS writes) ----
    const float* g = ws + (size_t)b * NROWS;
    if (tid < 64) fs[tid] = g[tid];
#pragma unroll
    for (int i = 0; i < 2; ++i) {
        const int e = (i * 256 + tid) * 4;                   // 0..2044
        float4 gi = *(const float4*)(g + 64 + e);            // ig[m*32+c]
        bf4_t vi = { (short)f2bf(gi.x), (short)f2bf(gi.y),
                     (short)f2bf(gi.z), (short)f2bf(gi.w) };
        *(bf4_t*)&IGs[(e >> 5) * 40 + (e & 31)] = vi;
        float4 go = *(const float4*)(g + 2112 + e);          // og[o*64+m]
        bf4_t vo = { (short)f2bf(go.x), (short)f2bf(go.y),
                     (short)f2bf(go.z), (short)f2bf(go.w) };
        *(bf4_t*)&OGs[(e >> 6) * 72 + (e & 63)] = vo;
    }
    // ---- stage X^T[p][c] (coalesced b32 reads, transposed b16 writes) ----
    const float* inb = inputs + (size_t)b * IN_CH * HW + tile;
#pragma unroll
    for (int i = 0; i < 16; ++i) {
        const int flat = i * 256 + tid;                      // 0..4095
        const int c = flat >> 7, p = flat & 127;
        Xt[p * 40 + c] = f2bf(inb[c * HW + p]);
    }
    __syncthreads();

    // ---- Phase A: D[p][m], wave w owns p-chunks {2w, 2w+1} x all 4 m-chunks
    bf8_t af[2], bg[4];
#pragma unroll
    for (int pc = 0; pc < 2; ++pc)
        af[pc] = *(const bf8_t*)&Xt[(w * 32 + pc * 16 + mlo) * 40 + quad * 8];
#pragma unroll
    for (int mc = 0; mc < 4; ++mc)
        bg[mc] = *(const bf8_t*)&IGs[(mc * 16 + mlo) * 40 + quad * 8];

    f32x4 acc[2][4];
#pragma unroll
    for (int pc = 0; pc < 2; ++pc)
#pragma unroll
        for (int mc = 0; mc < 4; ++mc) {
            acc[pc][mc] = (f32x4){0.f, 0.f, 0.f, 0.f};
            acc[pc][mc] = __builtin_amdgcn_mfma_f32_16x16x32_bf16(
                af[pc], bg[mc], acc[pc][mc], 0, 0, 0);
        }

    // ---- epilogue: float4 state read, ns = acc + st*f, float4 ns write,
    //      tanh -> Tt[p][m] (wave-private rows)
    const float* stb = state + (size_t)b * NMAPS * HW + tile;
    float*       nsb = out + OUT0_SZ + (size_t)b * NMAPS * HW + tile;
#pragma unroll
    for (int mc = 0; mc < 4; ++mc) {
        const int m = mc * 16 + mlo;
        const float fgt = fs[m];
#pragma unroll
        for (int pc = 0; pc < 2; ++pc) {
            const int p0 = w * 32 + pc * 16 + quad * 4;
            const float4 st = *(const float4*)(stb + (size_t)m * HW + p0);
            float4 ns;
            ns.x = acc[pc][mc][0] + st.x * fgt;
            ns.y = acc[pc][mc][1] + st.y * fgt;
            ns.z = acc[pc][mc][2] + st.z * fgt;
            ns.w = acc[pc][mc][3] + st.w * fgt;
            *(float4*)(nsb + (size_t)m * HW + p0) = ns;
            Tt[(p0 + 0) * 72 + m] = f2bf(fast_tanh(ns.x));
            Tt[(p0 + 1) * 72 + m] = f2bf(fast_tanh(ns.y));
            Tt[(p0 + 2) * 72 + m] = f2bf(fast_tanh(ns.z));
            Tt[(p0 + 3) * 72 + m] = f2bf(fast_tanh(ns.w));
        }
    }
    // no barrier: wave w reads only Tt rows it wrote

    // ---- Phase B: D[p][o] = T^T[p][m] x OG^T[m][o], K=64 -> 2 steps
    bf8_t ag[2][2], at[2][2];
#pragma unroll
    for (int oc = 0; oc < 2; ++oc)
#pragma unroll
        for (int ks = 0; ks < 2; ++ks)
            ag[oc][ks] = *(const bf8_t*)&OGs[(oc * 16 + mlo) * 72 + ks * 32 + quad * 8];
#pragma unroll
    for (int pc = 0; pc < 2; ++pc)
#pragma unroll
        for (int ks = 0; ks < 2; ++ks)
            at[pc][ks] = *(const bf8_t*)&Tt[(w * 32 + pc * 16 + mlo) * 72 + ks * 32 + quad * 8];

    f32x4 acc2[2][2];
#pragma unroll
    for (int pc = 0; pc < 2; ++pc)
#pragma unroll
        for (int oc = 0; oc < 2; ++oc) {
            acc2[pc][oc] = (f32x4){0.f, 0.f, 0.f, 0.f};
#pragma unroll
            for (int ks = 0; ks < 2; ++ks)
                acc2[pc][oc] = __builtin_amdgcn_mfma_f32_16x16x32_bf16(
                    at[pc][ks], ag[oc][ks], acc2[pc][oc], 0, 0, 0);
        }

    float* ob = out + (size_t)b * OUT_CH * HW + tile;
#pragma unroll
    for (int pc = 0; pc < 2; ++pc)
#pragma unroll
        for (int oc = 0; oc < 2; ++oc) {
            const int p0 = w * 32 + pc * 16 + quad * 4;
            const int o  = oc * 16 + mlo;
            float4 r;
            r.x = acc2[pc][oc][0];
            r.y = acc2[pc][oc][1];
            r.z = acc2[pc][oc][2];
            r.w = acc2[pc][oc][3];
            *(float4*)(ob + (size_t)o * HW + p0) = r;
        }
}

extern "C" void kernel_launch(void* const* d_in, const int* in_sizes, int n_in,
                              void* d_out, int out_size, void* d_ws, size_t ws_size,
                              hipStream_t stream) {
    const float* inputs   = (const float*)d_in[0];
    const float* state    = (const float*)d_in[1];
    const float* controls = (const float*)d_in[2];
    const float* W        = (const float*)d_in[3];
    float*       out      = (float*)d_out;
    float*       ws       = (float*)d_ws;

    ctrl_gemm<<<dim3(NROWS / 8), 256, 0, stream>>>(controls, W, ws);

    dim3 g2(HW / TILE, B_SZ);
    vstm_main<<<g2, 256, 0, stream>>>(inputs, state, ws, out);
}